// Round 5
// baseline (175.078 us; speedup 1.0000x reference)
//
#include <hip/hip_runtime.h>

// RNNT (Transducer) alpha-recursion loss, forward, mean reduction.
// B=4, T=512, U=100 (U+1=101 cols), V=1024, fp32.
//
// alpha[t][u] = lse(alpha[t-1][u] + blank[t-1][u], alpha[t][u-1] + emit[t][u-1])
// out = mean_b( -alpha[Tb-1][Ub] )
//
// R5: ONE kernel, 4 blocks (one per batch) x 320 threads (5 waves).
//  - Waves 0..3 (producers): each owns one component of the per-diagonal
//    gather -- wv0: blank[u0], wv1: blank[u1], wv2: emit[u0-1], wv3: emit[u0]
//    (u0 = 2*lane). Stream scattered values from the 847MB logits straight
//    into LDS chunks of CC=28 diagonals (fully unrolled -> ~1800 loads in
//    flight per block; one chunk fill ~ one HBM latency). log2-scaled.
//  - Wave 4 (consumer): DPP-wavefront DP over the LDS chunks; lane l owns
//    columns u=2l,2l+1; 4-step register ring hides ds_read latency; chain
//    ~40cy/step. Double-buffered chunks, __syncthreads pipeline.
//  This removes the old gather kernel, the 2.5MB g_PK HBM write+reread
//  (whose ~900cy-latency reads dominated the DP), and a kernel boundary.
//  LDS slot i of chunk c holds gathered diagonal r = c*CC + i - 1 (step s
//  consumes diagonal s-1; r=-1 slots are NEG automatically via t<0 mask).

constexpr int B = 4, T = 512, U = 100, Up1 = 101, V = 1024;
constexpr int CC = 28;            // diagonals per chunk; LDS = 2*4*CC*64*4 = 57344 B
constexpr int GROUPS = CC / 4;    // 7 consumer groups per chunk
constexpr float NEG = -1e30f;
constexpr float LOG2E = 1.44269504088896340736f;
constexpr float LN2 = 0.69314718055994530942f;

__device__ float g_ps[B];
__device__ int g_ctr = 0;

__device__ __forceinline__ int clampi(int x, int lo, int hi) {
  return x < lo ? lo : (x > hi ? hi : x);
}
__device__ __forceinline__ float fexp2(float x) {
  float r; asm("v_exp_f32 %0, %1" : "=v"(r) : "v"(x)); return r;
}
__device__ __forceinline__ float flog2(float x) {
  float r; asm("v_log_f32 %0, %1" : "=v"(r) : "v"(x)); return r;
}
// log2-domain logaddexp: max(a,b) + log2(1 + 2^(-|a-b|))
__device__ __forceinline__ float lse2(float a, float b) {
  float m = fmaxf(a, b);
  float d = a - b;
  float nd = fminf(d, -d);        // -|a-b|
  return m + flog2(1.0f + fexp2(nd));
}
// whole-wave shift: lane l receives lane l-1 (lane 0 keeps own; unused)
__device__ __forceinline__ float wave_shr1(float x) {
  int xi = __builtin_bit_cast(int, x);
  int r = __builtin_amdgcn_update_dpp(xi, xi, 0x138 /*WF_SR1*/, 0xF, 0xF, false);
  return __builtin_bit_cast(float, r);
}

__global__ __launch_bounds__(320, 1)
void rnnt_kernel(const float* __restrict__ logits,
                 const int* __restrict__ labels,
                 const int* __restrict__ logit_len,
                 const int* __restrict__ label_len,
                 float* __restrict__ out) {
  __shared__ float sB[2][4][CC][64];
  const int b = blockIdx.x;
  const int wv = threadIdx.x >> 6;     // 0..3 producers, 4 consumer
  const int lane = threadIdx.x & 63;
  const int Tb = clampi(logit_len[b], 1, T);
  const int Ub = clampi(label_len[b], 1, U);
  const int smax = Tb - 1 + Ub;        // diagonal of the answer cell
  const int nc = (smax + CC) / CC;     // ceil((smax+1)/CC) chunks

  // ---- producer setup: component -> (logits column u_q, emit?) ----
  const float* lg = logits + (size_t)b * T * Up1 * V;
  int u_q, is_emit;
  if (wv == 0)      { u_q = 2 * lane;     is_emit = 0; }
  else if (wv == 1) { u_q = 2 * lane + 1; is_emit = 0; }
  else if (wv == 2) { u_q = 2 * lane - 1; is_emit = 1; }
  else              { u_q = 2 * lane;     is_emit = 1; }
  const int ulim = is_emit ? Ub - 1 : Ub;
  const bool uok = (wv < 4) && (u_q >= 0) && (u_q <= ulim);
  int vidx = 0;
  if (wv < 4 && is_emit && u_q >= 0 && u_q < U)
    vidx = clampi(labels[b * U + u_q], 0, V - 1);
  const float* lgq = lg + (ptrdiff_t)u_q * V + vidx;   // deref'd only when uok
  const size_t tstride = (size_t)Up1 * V;

  // fill buffer BUF with diagonals r = BASE-1 .. BASE+CC-2 (slot i <- BASE+i-1)
#define FILL(BUF, BASE)                                                         \
  {                                                                             \
    float vals_[CC];                                                            \
    _Pragma("unroll")                                                           \
    for (int i_ = 0; i_ < CC; ++i_) {                                           \
      int t_ = (BASE) + i_ - 1 - u_q;                                           \
      vals_[i_] = (uok && t_ >= 0 && t_ < Tb)                                   \
                      ? LOG2E * lgq[(size_t)t_ * tstride] : NEG;                \
    }                                                                           \
    _Pragma("unroll")                                                           \
    for (int i_ = 0; i_ < CC; ++i_) sB[BUF][wv][i_][lane] = vals_[i_];          \
  }

  if (wv < 4) FILL(0, 0);
  __syncthreads();

  float first = NEG;                   // alpha[.][2*lane]
  float second = NEG;                  // alpha[.][2*lane+1]

  for (int c = 0; c < nc; ++c) {
    const int base = c * CC;
    if (wv < 4) {
      if (c + 1 < nc) FILL((c + 1) & 1, base + CC);
    } else {
      const int bb = c & 1;
      float rx[4], ry[4], rz[4], rw[4];
#pragma unroll
      for (int j = 0; j < 4; ++j) {
        rx[j] = sB[bb][0][j][lane]; ry[j] = sB[bb][1][j][lane];
        rz[j] = sB[bb][2][j][lane]; rw[j] = sB[bb][3][j][lane];
      }
      for (int g = 0; g < GROUPS; ++g) {
        float nx[4], ny[4], nz[4], nw[4];
        if (g + 1 < GROUPS) {
#pragma unroll
          for (int j = 0; j < 4; ++j) {
            int i2 = (g + 1) * 4 + j;
            nx[j] = sB[bb][0][i2][lane]; ny[j] = sB[bb][1][i2][lane];
            nz[j] = sB[bb][2][i2][lane]; nw[j] = sB[bb][3][i2][lane];
          }
        }
#pragma unroll
        for (int j = 0; j < 4; ++j) {
          int s = base + g * 4 + j;
          if (s <= smax) {                 // wave-uniform
            float pfB = wave_shr1(second); // neighbor's odd column, pre-update
            float oldA = first;
            int tA = s - 2 * lane;
            // column A: u = 2*lane (lanes 0..50)
            if (lane <= U / 2 && tA >= 0 && tA < T) {
              float up = (tA > 0) ? first + rx[j] : NEG;
              float lf = (lane > 0) ? pfB + rz[j] : NEG;
              float v = lse2(up, lf);
              if ((tA | lane) == 0) v = 0.0f;   // alpha[0][0] = 0
              first = v;
              if (tA == Tb - 1 && 2 * lane == Ub)
                __hip_atomic_store(&g_ps[b], v, __ATOMIC_RELEASE, __HIP_MEMORY_SCOPE_AGENT);
            }
            // column B: u = 2*lane+1 (lanes 0..49)
            int tB = tA - 1;
            if (lane <= (U - 2) / 2 && tB >= 0 && tB < T) {
              float up = (tB > 0) ? second + ry[j] : NEG;
              float lf = oldA + rw[j];
              float v = lse2(up, lf);
              second = v;
              if (tB == Tb - 1 && 2 * lane + 1 == Ub)
                __hip_atomic_store(&g_ps[b], v, __ATOMIC_RELEASE, __HIP_MEMORY_SCOPE_AGENT);
            }
          }
        }
        if (g + 1 < GROUPS) {
#pragma unroll
          for (int j = 0; j < 4; ++j) {
            rx[j] = nx[j]; ry[j] = ny[j]; rz[j] = nz[j]; rw[j] = nw[j];
          }
        }
      }
    }
    __syncthreads();
  }

  // last block to finish computes the mean (device-scope handshake)
  if (wv == 4 && lane == 0) {
    int old = __hip_atomic_fetch_add(&g_ctr, 1, __ATOMIC_ACQ_REL, __HIP_MEMORY_SCOPE_AGENT);
    if (old == B - 1) {
      float s = 0.0f;
      for (int i = 0; i < B; ++i)
        s += __hip_atomic_load(&g_ps[i], __ATOMIC_ACQUIRE, __HIP_MEMORY_SCOPE_AGENT);
      out[0] = -s * (LN2 / B);
      __hip_atomic_store(&g_ctr, 0, __ATOMIC_RELAXED, __HIP_MEMORY_SCOPE_AGENT);
    }
  }
#undef FILL
}

extern "C" void kernel_launch(void* const* d_in, const int* in_sizes, int n_in,
                              void* d_out, int out_size, void* d_ws, size_t ws_size,
                              hipStream_t stream) {
  const float* logits = (const float*)d_in[0];
  const int* labels = (const int*)d_in[1];
  const int* logit_len = (const int*)d_in[2];
  const int* label_len = (const int*)d_in[3];
  float* out = (float*)d_out;

  hipLaunchKernelGGL(rnnt_kernel, dim3(B), dim3(320), 0, stream,
                     logits, labels, logit_len, label_len, out);
}

// Round 7
// 47.091 us; speedup vs baseline: 3.7179x; 3.7179x over previous
//
#include <hip/hip_runtime.h>

// RNNT (Transducer) alpha-recursion loss, forward, mean reduction.
// B=4, T=512, U=100 (U+1=101 cols), V=1024, fp32.
//
// log-domain recurrence:
//   alpha[t][u] = lse(alpha[t-1][u] + blank[t-1][u], alpha[t][u-1] + emit[t][u-1])
// R7: linear-domain DP (recurrence is linear over (+,x)):
//   a[t][u] = a[t-1][u]*fB + a[t][u-1]*fE,  fB/fE = exp2(log2e*logit) (f32)
// with F64 STATE. R6's f32 state overflowed: the answer is ~-700 log2
// (stub round: |ref|=488 nats) and cross-lane spread + in-window drift
// exceed f32's +-127 exponent range. f64's +-1023 range + a wave-uniform
// reference-lane ldexp rescale every W=16 steps (exponent-exact, ~1 op/step
// amortized) keeps everything in range. Carried chain per step:
// 2xDPP shr (hi/lo) + v_mul_f64 + v_fma_f64 -- ZERO transcendentals
// (log-domain lse2 was ~50cy/step with 4 transcendental issues).
//
//  1) gather_kernel (wide, 612x4 blocks): scatter-gather blank (v=0) and
//     emit (v=label), rect-masked to cells reaching alpha[Tb-1][Ub],
//     stored as f32 exp2-FACTORS in anti-diagonal float4 rows (0 = -inf).
//  2) dp_kernel (4 blocks x 1 wave): lane l owns columns u=2l,2l+1; left
//     neighbor via DPP wave_shr:1 on both halves of the double. Modulo-3
//     software pipeline of 16-row float4 groups (~32 rows / ~1000cy of
//     prefetch distance covers HBM latency; 192 VGPRs of buffer, 1 wave).
//     Answer produced at step smax, extracted post-loop as
//     exponent + log2(mantissa) + accumulated scale.

constexpr int B = 4, T = 512, U = 100, Up1 = 101, V = 1024;
constexpr int DIAGS = T + U;       // 612
constexpr int W = 16;              // DP steps per load group
constexpr float LOG2E = 1.44269504088896340736f;
constexpr float LN2 = 0.69314718055994530942f;

__device__ float4 g_PK[(size_t)B * DIAGS * 64];
__device__ float g_ps[B];          // per-sample log2(alpha_final)
__device__ int g_ctr = 0;

__device__ __forceinline__ int clampi(int x, int lo, int hi) {
  return x < lo ? lo : (x > hi ? hi : x);
}
__device__ __forceinline__ float fexp2(float x) {
  float r; asm("v_exp_f32 %0, %1" : "=v"(r) : "v"(x)); return r;
}
__device__ __forceinline__ float flog2(float x) {
  float r; asm("v_log_f32 %0, %1" : "=v"(r) : "v"(x)); return r;
}
// whole-wave shift by 1 on a double: lane l receives lane l-1's value
// (lane 0 keeps its own; its left factor is 0 so the value never contributes)
__device__ __forceinline__ double wave_shr1_f64(double x) {
  int hi = __double2hiint(x), lo = __double2loint(x);
  hi = __builtin_amdgcn_update_dpp(hi, hi, 0x138 /*WF_SR1*/, 0xF, 0xF, false);
  lo = __builtin_amdgcn_update_dpp(lo, lo, 0x138 /*WF_SR1*/, 0xF, 0xF, false);
  return __hiloint2double(hi, lo);
}

__global__ __launch_bounds__(256) void gather_kernel(const float* __restrict__ logits,
                                                     const int* __restrict__ labels,
                                                     const int* __restrict__ logit_len,
                                                     const int* __restrict__ label_len) {
  const int b = blockIdx.y;
  const int r = blockIdx.x * 4 + (threadIdx.x >> 6);   // anti-diagonal row
  const int l = threadIdx.x & 63;                      // DP lane slot
  const int Tb = clampi(logit_len[b], 1, T);
  const int Ub = clampi(label_len[b], 1, U);
  if (r > Tb - 1 + Ub) return;                         // beyond answer diagonal

  const float* lg = logits + (size_t)b * T * Up1 * V;
  const int u0 = 2 * l, u1 = u0 + 1;
  float4 v;
  v.x = v.y = v.z = v.w = 0.0f;                        // 0 == linear -inf

  int tx = r - u0;                                     // blank[tx][u0]
  if (u0 <= Ub && tx >= 0 && tx <= Tb - 1)
    v.x = fexp2(LOG2E * lg[((size_t)tx * Up1 + u0) * V]);
  int ty = r - u1;                                     // blank[ty][u1]
  if (u1 <= Ub && ty >= 0 && ty <= Tb - 1)
    v.y = fexp2(LOG2E * lg[((size_t)ty * Up1 + u1) * V]);
  int tz = r - u0 + 1;                                 // emit[tz][u0-1]
  if (u0 >= 1 && u0 <= Ub && tz >= 0 && tz <= Tb - 1) {
    int lab = clampi(labels[b * U + (u0 - 1)], 0, V - 1);
    v.z = fexp2(LOG2E * lg[((size_t)tz * Up1 + (u0 - 1)) * V + lab]);
  }
  int tw = r - u0;                                     // emit[tw][u0]
  if (u0 <= Ub - 1 && tw >= 0 && tw <= Tb - 1) {
    int lab = clampi(labels[b * U + u0], 0, V - 1);
    v.w = fexp2(LOG2E * lg[((size_t)tw * Up1 + u0) * V + lab]);
  }
  g_PK[((size_t)b * DIAGS + r) * 64 + l] = v;
}

__global__ __launch_bounds__(64) void dp_kernel(const int* __restrict__ logit_len,
                                                const int* __restrict__ label_len,
                                                float* __restrict__ out) {
  const int b = blockIdx.x;
  const int lane = threadIdx.x;
  const int Tb = clampi(logit_len[b], 1, T);
  const int Ub = clampi(label_len[b], 1, U);
  const int smax = Tb - 1 + Ub;        // diagonal (= step) of the answer cell
  const float4* PK = g_PK + (size_t)b * DIAGS * 64;

  // linear-domain f64 state: A = alpha[.][2*lane], Bc = alpha[.][2*lane+1]
  double A = (lane == 0) ? 1.0 : 0.0;  // alpha[0][0] = 1 (diag 0 done)
  double Bc = 0.0;
  int scale = 0;                       // accumulated log2 rescale

  float4 ba[W], bb[W], bc[W];

  // group g holds rows g*W .. g*W+W-1 (step s consumes row s-1)
#define LOADG(buf, grp)                                                        \
  {                                                                            \
    int base_ = (grp) * W;                                                     \
    _Pragma("unroll")                                                          \
    for (int j_ = 0; j_ < W; ++j_) {                                           \
      int r_ = base_ + j_; if (r_ > DIAGS - 1) r_ = DIAGS - 1;                 \
      buf[j_] = PK[(size_t)r_ * 64 + lane];                                    \
    }                                                                          \
  }

  // window grp = steps grp*W+1 .. grp*W+W; then wave-uniform ldexp rescale
#define STEPS(buf, grp)                                                        \
  {                                                                            \
    int sb_ = (grp) * W + 1;                                                   \
    _Pragma("unroll")                                                          \
    for (int j_ = 0; j_ < W; ++j_) {                                           \
      int s_ = sb_ + j_;                                                       \
      if (s_ <= smax) {                                                        \
        double fx_ = (double)buf[j_].x, fy_ = (double)buf[j_].y;               \
        double fz_ = (double)buf[j_].z, fw_ = (double)buf[j_].w;               \
        double shrB_ = wave_shr1_f64(Bc);                                      \
        double na_ = fma(A, fx_, shrB_ * fz_);                                 \
        double nb_ = fma(Bc, fy_, A * fw_);                                    \
        A = na_; Bc = nb_;                                                     \
      }                                                                        \
    }                                                                          \
    int s2_ = (grp) * W + W; if (s2_ > smax) s2_ = smax;                       \
    int ulo_ = s2_ - (Tb - 1); if (ulo_ < 0) ulo_ = 0;                         \
    int uhi_ = s2_ < Ub ? s2_ : Ub;                                            \
    int um_ = (ulo_ + uhi_) >> 1;                                              \
    double ref_ = (um_ & 1) ? __shfl(Bc, um_ >> 1, 64)                         \
                            : __shfl(A, um_ >> 1, 64);                         \
    if (ref_ != 0.0) {                                                         \
      int e_ = ((__double2hiint(ref_) >> 20) & 0x7ff) - 1023;                  \
      A = ldexp(A, -e_); Bc = ldexp(Bc, -e_); scale += e_;                     \
    }                                                                          \
  }

  const int NW = (smax + W - 1) / W;   // windows covering steps 1..smax
  LOADG(ba, 0);
  if (NW > 1) LOADG(bb, 1);
  for (int k = 0; k < NW; k += 3) {
    if (k + 2 < NW) LOADG(bc, k + 2);
    STEPS(ba, k);
    if (k + 1 < NW) {
      if (k + 3 < NW) LOADG(ba, k + 3);
      STEPS(bb, k + 1);
      if (k + 2 < NW) {
        if (k + 4 < NW) LOADG(bb, k + 4);
        STEPS(bc, k + 2);
      }
    }
  }

  // answer cell (Tb-1, Ub) was produced at step smax (the final step)
  const int ansLane = Ub >> 1;
  double va = __shfl(A, ansLane, 64);
  double vb = __shfl(Bc, ansLane, 64);
  double v = (Ub & 1) ? vb : va;
  // log2(v) + scale, via exponent extraction + f32 log2 of mantissa in [1,2)
  int ev = ((__double2hiint(v) >> 20) & 0x7ff) - 1023;
  double m = ldexp(v, -ev);
  float lg2 = (float)ev + flog2((float)m) + (float)scale;

  if (lane == 0) {
    __hip_atomic_store(&g_ps[b], lg2, __ATOMIC_RELEASE, __HIP_MEMORY_SCOPE_AGENT);
    int old = __hip_atomic_fetch_add(&g_ctr, 1, __ATOMIC_ACQ_REL, __HIP_MEMORY_SCOPE_AGENT);
    if (old == B - 1) {
      float s = 0.0f;
      for (int i = 0; i < B; ++i)
        s += __hip_atomic_load(&g_ps[i], __ATOMIC_ACQUIRE, __HIP_MEMORY_SCOPE_AGENT);
      out[0] = -s * (LN2 / B);
      __hip_atomic_store(&g_ctr, 0, __ATOMIC_RELAXED, __HIP_MEMORY_SCOPE_AGENT);
    }
  }
#undef LOADG
#undef STEPS
}

extern "C" void kernel_launch(void* const* d_in, const int* in_sizes, int n_in,
                              void* d_out, int out_size, void* d_ws, size_t ws_size,
                              hipStream_t stream) {
  const float* logits = (const float*)d_in[0];
  const int* labels = (const int*)d_in[1];
  const int* logit_len = (const int*)d_in[2];
  const int* label_len = (const int*)d_in[3];
  float* out = (float*)d_out;

  hipLaunchKernelGGL(gather_kernel, dim3(DIAGS / 4, B), dim3(256), 0, stream,
                     logits, labels, logit_len, label_len);
  hipLaunchKernelGGL(dp_kernel, dim3(B), dim3(64), 0, stream,
                     logit_len, label_len, out);
}